// Round 8
// baseline (1384.536 us; speedup 1.0000x reference)
//
#include <hip/hip_runtime.h>
#include <math.h>

#define VOCAB 64
#define H 64
#define BB 256
#define LL 2048

typedef float v2f __attribute__((ext_vector_type(2)));

// 64-lane wave sum via DPP (row_shr 1/2/4/8, row_bcast15, row_bcast31), then
// broadcast total from lane 63. All VALU-pipe, no LDS latency.
__device__ __forceinline__ float wave_sum_dpp(float x) {
  int t;
  float r = x;
  t = __builtin_amdgcn_update_dpp(0, __float_as_int(r), 0x111, 0xf, 0xf, true); r += __int_as_float(t);
  t = __builtin_amdgcn_update_dpp(0, __float_as_int(r), 0x112, 0xf, 0xf, true); r += __int_as_float(t);
  t = __builtin_amdgcn_update_dpp(0, __float_as_int(r), 0x114, 0xf, 0xf, true); r += __int_as_float(t);
  t = __builtin_amdgcn_update_dpp(0, __float_as_int(r), 0x118, 0xf, 0xf, true); r += __int_as_float(t);
  t = __builtin_amdgcn_update_dpp(0, __float_as_int(r), 0x142, 0xf, 0xf, true); r += __int_as_float(t);
  t = __builtin_amdgcn_update_dpp(0, __float_as_int(r), 0x143, 0xf, 0xf, true); r += __int_as_float(t);
  return __int_as_float(__builtin_amdgcn_readlane(__float_as_int(r), 63));
}

// Phase 1: hidden depends only on the token id -> precompute 64 hidden vectors.
__global__ __launch_bounds__(64, 1) void encode_kernel(
    const float* __restrict__ embed, const float* __restrict__ W1,
    const float* __restrict__ b1, const float* __restrict__ W2,
    const float* __restrict__ b2, const float* __restrict__ gamma,
    const float* __restrict__ beta, float* __restrict__ table,
    float* __restrict__ kkg) {
  const int c = blockIdx.x;
  const int j = threadIdx.x;
  __shared__ float hs[H];
  __shared__ float zs[2 * H];
  const float h = embed[c * H + j];
  hs[j] = h;
  __syncthreads();
  float z0 = b1[j], z1 = b1[j + H];
#pragma unroll 8
  for (int i = 0; i < H; ++i) {
    const float hi = hs[i];
    z0 = fmaf(hi, W1[i * 2 * H + j], z0);
    z1 = fmaf(hi, W1[i * 2 * H + j + H], z1);
  }
  z0 = fmaxf(z0, 0.f);
  z1 = fmaxf(z1, 0.f);
  zs[j] = z0;
  zs[j + H] = z1;
  __syncthreads();
  float ff = b2[j];
#pragma unroll 8
  for (int m = 0; m < 2 * H; ++m) ff = fmaf(zs[m], W2[m * H + j], ff);
  const float x = h + ff;
  const float mu = wave_sum_dpp(x) * (1.f / 64.f);
  const float d = x - mu;
  const float var = wave_sum_dpp(d * d) * (1.f / 64.f);
  const float y = d * (1.f / sqrtf(var + 1e-5f)) * gamma[j] + beta[j];
  table[c * H + j] = y;
  const float s2 = wave_sum_dpp(y * y);
  if (j == 0) kkg[c] = s2;
}

// Phase 2+3: per-batch sequential scan, TWO independent batches per wave.
// Grid = 128 blocks x 1 wave; wave handles batches b and b+128. The two
// recurrence chains are independent, so each one's LDS latency and
// divide/DPP-reduce dependency chain hides under the other's FMA issue.
// Per-batch arithmetic order is identical to the round-5 passing kernel.
__global__ __launch_bounds__(64, 1) void scan_kernel(
    const int* __restrict__ seq, const float* __restrict__ table,
    const float* __restrict__ kkg, const float* __restrict__ Wr,
    const float* __restrict__ br, const float* __restrict__ Wo,
    const float* __restrict__ bo, float* __restrict__ out,
    float* __restrict__ counts) {
  const int b0 = blockIdx.x;
  const int b1 = blockIdx.x + (BB / 2);
  const int lane = threadIdx.x;
  __shared__ float T[H * VOCAB];   // 16 KB: table, row c = key vector for token c
  __shared__ float KK[VOCAB];
  __shared__ int tok0[LL];         // 8 KB each: token streams
  __shared__ int tok1[LL];
  __shared__ float xv[2][H];
  __shared__ float yv[2][H];

  {
    const float4* src = (const float4*)table;
    float4* dst = (float4*)T;
#pragma unroll
    for (int q = 0; q < 16; ++q) dst[q * 64 + lane] = src[q * 64 + lane];
    KK[lane] = kkg[lane];
    const int4* s0 = (const int4*)(seq + (long)b0 * LL);
    const int4* s1 = (const int4*)(seq + (long)b1 * LL);
    int4* d0 = (int4*)tok0;
    int4* d1 = (int4*)tok1;
#pragma unroll
    for (int q = 0; q < 8; ++q) {
      d0[q * 64 + lane] = s0[q * 64 + lane];
      d1[q * 64 + lane] = s1[q * 64 + lane];
    }
  }
  __syncthreads();

  v2f M0[32], M1[32];
#pragma unroll
  for (int r = 0; r < 32; ++r) { M0[r] = (v2f){0.f, 0.f}; M1[r] = (v2f){0.f, 0.f}; }
  float wc0 = 0.f, wc1 = 0.f;

  // Carried scalars: tokens c(t), c(t+1); per-lane k and k.k for t, t+1.
  int c0 = tok0[0], cn0 = tok0[1];
  int c1 = tok1[0], cn1 = tok1[1];
  float sc0 = T[c0 * H + lane], kk0 = KK[c0];
  float scn0 = T[cn0 * H + lane], kkn0 = KK[cn0];
  float sc1 = T[c1 * H + lane], kk1 = KK[c1];
  float scn1 = T[cn1 * H + lane], kkn1 = KK[cn1];
  v2f vA0 = (v2f){0.f, 0.f}, vB0 = (v2f){0.f, 0.f};  // M=0 -> vp(0)=0
  v2f vA1 = (v2f){0.f, 0.f}, vB1 = (v2f){0.f, 0.f};

  for (int t = 0; t < LL - 1; ++t) {
    // Prefetch step-(t+2) tokens + scalars for both batches (plain loads;
    // their latency hides under this iteration's compute of two chains).
    const int tp = (t + 2 < LL) ? t + 2 : LL - 1;
    const int cp0 = tok0[tp], cp1 = tok1[tp];
    const float scp0 = T[cp0 * H + lane], kkp0 = KK[cp0];
    const float scp1 = T[cp1 * H + lane], kkp1 = KK[cp1];
    // Row pointers for this step (update row c_t, dot row c_{t+1}).
    const float4* u0 = (const float4*)(T + c0 * H);
    const float4* d0 = (const float4*)(T + cn0 * H);
    const float4* u1 = (const float4*)(T + c1 * H);
    const float4* d1 = (const float4*)(T + cn1 * H);

    const float vp0 = (vA0.x + vA0.y) + (vB0.x + vB0.y);
    const float vp1 = (vA1.x + vA1.y) + (vB1.x + vB1.y);
    const float dv0 = sc0 - vp0 / (kk0 + 1e-6f);
    const float dv1 = sc1 - vp1 / (kk1 + 1e-6f);
    const float a0 = dv0 * (2.f * vp0 + dv0 * kk0);
    const float a1 = dv1 * (2.f * vp1 + dv1 * kk1);
    const float s0 = wave_sum_dpp(a0);   // two independent DPP chains
    const float s1 = wave_sum_dpp(a1);
    const float g0 = s0 > 0.f ? dv0 : 0.f;
    const float g1 = s1 > 0.f ? dv1 : 0.f;
    wc0 += s0 > 0.f ? 1.f : 0.f;
    wc1 += s1 > 0.f ? 1.f : 0.f;
    const v2f d20 = (v2f){g0, g0};
    const v2f d21 = (v2f){g1, g1};

    v2f nA0 = (v2f){0.f, 0.f}, nB0 = (v2f){0.f, 0.f};
    v2f nA1 = (v2f){0.f, 0.f}, nB1 = (v2f){0.f, 0.f};
#pragma unroll
    for (int q = 0; q < 16; ++q) {
      const float4 kv0 = u0[q];
      const float4 kn0 = d0[q];
      const float4 kv1 = u1[q];
      const float4 kn1 = d1[q];
      const v2f kva0 = (v2f){kv0.x, kv0.y}, kvb0 = (v2f){kv0.z, kv0.w};
      const v2f kna0 = (v2f){kn0.x, kn0.y}, knb0 = (v2f){kn0.z, kn0.w};
      const v2f kva1 = (v2f){kv1.x, kv1.y}, kvb1 = (v2f){kv1.z, kv1.w};
      const v2f kna1 = (v2f){kn1.x, kn1.y}, knb1 = (v2f){kn1.z, kn1.w};
      M0[2 * q]     = __builtin_elementwise_fma(d20, kva0, M0[2 * q]);
      M0[2 * q + 1] = __builtin_elementwise_fma(d20, kvb0, M0[2 * q + 1]);
      nA0 = __builtin_elementwise_fma(M0[2 * q],     kna0, nA0);
      nB0 = __builtin_elementwise_fma(M0[2 * q + 1], knb0, nB0);
      M1[2 * q]     = __builtin_elementwise_fma(d21, kva1, M1[2 * q]);
      M1[2 * q + 1] = __builtin_elementwise_fma(d21, kvb1, M1[2 * q + 1]);
      nA1 = __builtin_elementwise_fma(M1[2 * q],     kna1, nA1);
      nB1 = __builtin_elementwise_fma(M1[2 * q + 1], knb1, nB1);
    }
    vA0 = nA0; vB0 = nB0; vA1 = nA1; vB1 = nB1;
    c0 = cn0; cn0 = cp0; sc0 = scn0; kk0 = kkn0; scn0 = scp0; kkn0 = kkp0;
    c1 = cn1; cn1 = cp1; sc1 = scn1; kk1 = kkn1; scn1 = scp1; kkn1 = kkp1;
  }

  // The last fused dot used row toks[LL-1]: vp == ctx[lane] per batch, in the
  // same accumulation order as the reference epilogue path used before.
  xv[0][lane] = (vA0.x + vA0.y) + (vB0.x + vB0.y);
  xv[1][lane] = (vA1.x + vA1.y) + (vB1.x + vB1.y);
  __syncthreads();
  float t10 = br[lane], t11 = br[lane];
#pragma unroll 8
  for (int i = 0; i < H; ++i) {
    const float w = Wr[i * H + lane];
    t10 = fmaf(xv[0][i], w, t10);
    t11 = fmaf(xv[1][i], w, t11);
  }
  yv[0][lane] = t10;
  yv[1][lane] = t11;
  __syncthreads();
  float lg0 = bo[lane], lg1 = bo[lane];
#pragma unroll 8
  for (int m = 0; m < H; ++m) {
    const float w = Wo[m * VOCAB + lane];
    lg0 = fmaf(yv[0][m], w, lg0);
    lg1 = fmaf(yv[1][m], w, lg1);
  }
  out[(long)b0 * H + lane] = lg0;
  out[(long)b1 * H + lane] = lg1;
  if (lane == 0) { counts[b0] = wc0; counts[b1] = wc1; }
}

__global__ __launch_bounds__(256, 1) void finalize_kernel(const float* __restrict__ counts,
                                                          float* __restrict__ out) {
  const int lane = threadIdx.x;  // 256 threads
  __shared__ float sbuf[BB];
  sbuf[lane] = counts[lane];
  __syncthreads();
  for (int off = BB / 2; off > 0; off >>= 1) {
    if (lane < off) sbuf[lane] += sbuf[lane + off];
    __syncthreads();
  }
  if (lane == 0) out[BB * H] = sbuf[0] / (float)(BB * (LL - 1));
}

extern "C" void kernel_launch(void* const* d_in, const int* in_sizes, int n_in,
                              void* d_out, int out_size, void* d_ws, size_t ws_size,
                              hipStream_t stream) {
  const int* seq      = (const int*)d_in[0];
  const float* embed  = (const float*)d_in[1];
  const float* W1     = (const float*)d_in[2];
  const float* b1     = (const float*)d_in[3];
  const float* W2     = (const float*)d_in[4];
  const float* b2     = (const float*)d_in[5];
  const float* gamma  = (const float*)d_in[6];
  const float* beta   = (const float*)d_in[7];
  const float* Wr     = (const float*)d_in[8];
  const float* br     = (const float*)d_in[9];
  const float* Wo     = (const float*)d_in[10];
  const float* bo     = (const float*)d_in[11];
  float* out = (float*)d_out;

  float* table  = (float*)d_ws;          // 64*64 f32
  float* kkg    = table + VOCAB * H;     // 64 f32
  float* counts = kkg + VOCAB;           // 256 f32

  encode_kernel<<<VOCAB, H, 0, stream>>>(embed, W1, b1, W2, b2, gamma, beta, table, kkg);
  scan_kernel<<<BB / 2, H, 0, stream>>>(seq, table, kkg, Wr, br, Wo, bo, out, counts);
  finalize_kernel<<<1, BB, 0, stream>>>(counts, out);
}

// Round 9
// 760.866 us; speedup vs baseline: 1.8197x; 1.8197x over previous
//
#include <hip/hip_runtime.h>
#include <math.h>

#define VOCAB 64
#define H 64
#define BB 256
#define LL 2048

typedef float v2f __attribute__((ext_vector_type(2)));

// Keep a value live in arch VGPRs past this point (placed AFTER the value's
// natural consumer, so it costs no extra wait and cannot be re-materialized
// from LDS by the scheduler).
#define PIN4(f) asm volatile("" : "+v"(f.x), "+v"(f.y), "+v"(f.z), "+v"(f.w))

// 64-lane wave sum via DPP (row_shr 1/2/4/8, row_bcast15, row_bcast31), then
// broadcast total from lane 63. All VALU-pipe, no LDS latency.
__device__ __forceinline__ float wave_sum_dpp(float x) {
  int t;
  float r = x;
  t = __builtin_amdgcn_update_dpp(0, __float_as_int(r), 0x111, 0xf, 0xf, true); r += __int_as_float(t);
  t = __builtin_amdgcn_update_dpp(0, __float_as_int(r), 0x112, 0xf, 0xf, true); r += __int_as_float(t);
  t = __builtin_amdgcn_update_dpp(0, __float_as_int(r), 0x114, 0xf, 0xf, true); r += __int_as_float(t);
  t = __builtin_amdgcn_update_dpp(0, __float_as_int(r), 0x118, 0xf, 0xf, true); r += __int_as_float(t);
  t = __builtin_amdgcn_update_dpp(0, __float_as_int(r), 0x142, 0xf, 0xf, true); r += __int_as_float(t);
  t = __builtin_amdgcn_update_dpp(0, __float_as_int(r), 0x143, 0xf, 0xf, true); r += __int_as_float(t);
  return __int_as_float(__builtin_amdgcn_readlane(__float_as_int(r), 63));
}

// Phase 1: hidden depends only on the token id -> precompute 64 hidden vectors.
__global__ __launch_bounds__(64, 1) void encode_kernel(
    const float* __restrict__ embed, const float* __restrict__ W1,
    const float* __restrict__ b1, const float* __restrict__ W2,
    const float* __restrict__ b2, const float* __restrict__ gamma,
    const float* __restrict__ beta, float* __restrict__ table,
    float* __restrict__ kkg) {
  const int c = blockIdx.x;
  const int j = threadIdx.x;
  __shared__ float hs[H];
  __shared__ float zs[2 * H];
  const float h = embed[c * H + j];
  hs[j] = h;
  __syncthreads();
  float z0 = b1[j], z1 = b1[j + H];
#pragma unroll 8
  for (int i = 0; i < H; ++i) {
    const float hi = hs[i];
    z0 = fmaf(hi, W1[i * 2 * H + j], z0);
    z1 = fmaf(hi, W1[i * 2 * H + j + H], z1);
  }
  z0 = fmaxf(z0, 0.f);
  z1 = fmaxf(z1, 0.f);
  zs[j] = z0;
  zs[j + H] = z1;
  __syncthreads();
  float ff = b2[j];
#pragma unroll 8
  for (int m = 0; m < 2 * H; ++m) ff = fmaf(zs[m], W2[m * H + j], ff);
  const float x = h + ff;
  const float mu = wave_sum_dpp(x) * (1.f / 64.f);
  const float d = x - mu;
  const float var = wave_sum_dpp(d * d) * (1.f / 64.f);
  const float y = d * (1.f / sqrtf(var + 1e-5f)) * gamma[j] + beta[j];
  table[c * H + j] = y;
  const float s2 = wave_sum_dpp(y * y);
  if (j == 0) kkg[c] = s2;
}

// One scan step. R = carried row k(c_t) (this step's UPDATE row; it was last
// step's dot row, pinned in registers). X <- fresh row k(c_{t+1}) (this
// step's DOT row), loaded once per step: 16 ds_read_b128 = the only bulk
// crossbar traffic. After the fused q-loop, X is pinned and becomes next
// step's R. Arithmetic order identical to rounds 2-5 (bit-exact).
#define STEP(T_IDX, R, X)                                                    \
  {                                                                          \
    const int tpre = ((T_IDX) + 3 < LL) ? (T_IDX) + 3 : LL - 1;              \
    const int cin = toks[tpre];          /* c_{t+3} */                       \
    const float scp = T[cnn * H + lane]; /* k_{c_{t+2}}[lane] */             \
    const float kkp = KK[cnn];                                               \
    const float4* xp = (const float4*)(T + cn * H);                          \
    _Pragma("unroll")                                                        \
    for (int q = 0; q < 16; ++q) X[q] = xp[q];                               \
    const float vp = (vpA.x + vpA.y) + (vpB.x + vpB.y);                      \
    const float dv = sc - vp / (kk + 1e-6f);                                 \
    const float aa = dv * (2.f * vp + dv * kk);                              \
    const float s = wave_sum_dpp(aa);                                        \
    const float dvg = s > 0.f ? dv : 0.f;                                    \
    wcount += s > 0.f ? 1.f : 0.f;                                           \
    const v2f dv2 = (v2f){dvg, dvg};                                         \
    v2f nA = (v2f){0.f, 0.f}, nB = (v2f){0.f, 0.f};                          \
    _Pragma("unroll")                                                        \
    for (int q = 0; q < 16; ++q) {                                           \
      const float4 kv4 = R[q];                                               \
      const float4 kn4 = X[q];                                               \
      const v2f kva = (v2f){kv4.x, kv4.y}, kvb = (v2f){kv4.z, kv4.w};        \
      const v2f kna = (v2f){kn4.x, kn4.y}, knb = (v2f){kn4.z, kn4.w};        \
      M2[2 * q]     = __builtin_elementwise_fma(dv2, kva, M2[2 * q]);        \
      M2[2 * q + 1] = __builtin_elementwise_fma(dv2, kvb, M2[2 * q + 1]);    \
      nA = __builtin_elementwise_fma(M2[2 * q],     kna, nA);                \
      nB = __builtin_elementwise_fma(M2[2 * q + 1], knb, nB);                \
    }                                                                        \
    vpA = nA; vpB = nB;                                                      \
    _Pragma("unroll")                                                        \
    for (int q = 0; q < 16; ++q) PIN4(X[q]); /* X stays live -> next R */    \
    cn = cnn; cnn = cin;                                                     \
    sc = scn; kk = kkn; scn = scp; kkn = kkp;                                \
  }

// Phase 2+3: per-batch sequential scan. One block = one wave = one batch.
// Lane i owns row M[i][:] (64 VGPRs). Row carry: M(64)+R(64)+X(64)+~30 misc
// ~= 222 arch VGPRs < 256 ceiling. Per-step crossbar: 16 b128 + 3 b32.
__global__ __launch_bounds__(64, 1) void scan_kernel(
    const int* __restrict__ seq, const float* __restrict__ table,
    const float* __restrict__ kkg, const float* __restrict__ Wr,
    const float* __restrict__ br, const float* __restrict__ Wo,
    const float* __restrict__ bo, float* __restrict__ out,
    float* __restrict__ counts) {
  const int b = blockIdx.x;
  const int lane = threadIdx.x;
  __shared__ float T[H * VOCAB];   // 16 KB: table, row c = key vector for token c
  __shared__ float KK[VOCAB];
  __shared__ int toks[LL];         // 8 KB: this batch's token stream
  __shared__ float xv[H];

  {
    const float4* src = (const float4*)table;
    float4* dst = (float4*)T;
#pragma unroll
    for (int q = 0; q < 16; ++q) dst[q * 64 + lane] = src[q * 64 + lane];
    KK[lane] = kkg[lane];
    const int4* ssrc = (const int4*)(seq + (long)b * LL);
    int4* sdst = (int4*)toks;
#pragma unroll
    for (int q = 0; q < 8; ++q) sdst[q * 64 + lane] = ssrc[q * 64 + lane];
  }
  __syncthreads();

  v2f M2[32];
#pragma unroll
  for (int r = 0; r < 32; ++r) M2[r] = (v2f){0.f, 0.f};
  float wcount = 0.f;

  // Prologue: carried row R = row(c_0); scalars for steps 0 and 1.
  float4 RA[16], RB[16];
  const int c0 = toks[0];
  int cn = toks[1], cnn = toks[2];
  float sc = T[c0 * H + lane], kk = KK[c0];
  float scn = T[cn * H + lane], kkn = KK[cn];
  {
    const float4* r0 = (const float4*)(T + c0 * H);
#pragma unroll
    for (int q = 0; q < 16; ++q) RA[q] = r0[q];
#pragma unroll
    for (int q = 0; q < 16; ++q) PIN4(RA[q]);
  }
  v2f vpA = (v2f){0.f, 0.f}, vpB = (v2f){0.f, 0.f};  // M=0 -> vp(0)=0

  int t = 0;
  for (int it = 0; it < 1023; ++it) {  // 1023*2 = 2046 steps
    STEP(t, RA, RB); ++t;
    STEP(t, RB, RA); ++t;
  }
  STEP(t, RA, RB);                     // t = 2046, last step; dot row = toks[2047]

  // The last fused dot used row toks[LL-1]: vp == ctx[lane] in the same
  // accumulation order as before.
  xv[lane] = (vpA.x + vpA.y) + (vpB.x + vpB.y);
  __syncthreads();
  float t1 = br[lane];
#pragma unroll 8
  for (int i = 0; i < H; ++i) t1 = fmaf(xv[i], Wr[i * H + lane], t1);
  __syncthreads();
  xv[lane] = t1;
  __syncthreads();
  float lg = bo[lane];
#pragma unroll 8
  for (int m = 0; m < H; ++m) lg = fmaf(xv[m], Wo[m * H + lane], lg);
  out[(long)b * H + lane] = lg;
  if (lane == 0) counts[b] = wcount;
}

__global__ __launch_bounds__(256, 1) void finalize_kernel(const float* __restrict__ counts,
                                                          float* __restrict__ out) {
  const int lane = threadIdx.x;  // 256 threads
  __shared__ float sbuf[BB];
  sbuf[lane] = counts[lane];
  __syncthreads();
  for (int off = BB / 2; off > 0; off >>= 1) {
    if (lane < off) sbuf[lane] += sbuf[lane + off];
    __syncthreads();
  }
  if (lane == 0) out[BB * H] = sbuf[0] / (float)(BB * (LL - 1));
}

extern "C" void kernel_launch(void* const* d_in, const int* in_sizes, int n_in,
                              void* d_out, int out_size, void* d_ws, size_t ws_size,
                              hipStream_t stream) {
  const int* seq      = (const int*)d_in[0];
  const float* embed  = (const float*)d_in[1];
  const float* W1     = (const float*)d_in[2];
  const float* b1     = (const float*)d_in[3];
  const float* W2     = (const float*)d_in[4];
  const float* b2     = (const float*)d_in[5];
  const float* gamma  = (const float*)d_in[6];
  const float* beta   = (const float*)d_in[7];
  const float* Wr     = (const float*)d_in[8];
  const float* br     = (const float*)d_in[9];
  const float* Wo     = (const float*)d_in[10];
  const float* bo     = (const float*)d_in[11];
  float* out = (float*)d_out;

  float* table  = (float*)d_ws;          // 64*64 f32
  float* kkg    = table + VOCAB * H;     // 64 f32
  float* counts = kkg + VOCAB;           // 256 f32

  encode_kernel<<<VOCAB, H, 0, stream>>>(embed, W1, b1, W2, b2, gamma, beta, table, kkg);
  scan_kernel<<<BB, H, 0, stream>>>(seq, table, kkg, Wr, br, Wo, bo, out, counts);
  finalize_kernel<<<1, BB, 0, stream>>>(counts, out);
}